// Round 4
// baseline (147.449 us; speedup 1.0000x reference)
//
#include <hip/hip_runtime.h>

// Problem constants (match reference)
#define BB 128
#define SS 8192
#define VV 128000

// Output element offsets (flat float32 view of d_out, tuple return order)
#define OFF_TOK 0
#define OFF_LTI (OFF_TOK + BB)
#define OFF_MASK (OFF_LTI + BB)            // 256
#define OFF_GEN (OFF_MASK + BB * SS)       // 1048832
#define OFF_STR (OFF_GEN + BB * SS)        // 2097408
#define OFF_GI  (OFF_STR + BB * SS)        // 3145984
#define OFF_CNT (OFF_GI + BB)              // 3146112

// Native clang vectors — required by __builtin_nontemporal_store
typedef float f32x4 __attribute__((ext_vector_type(4)));
typedef int   i32x4 __attribute__((ext_vector_type(4)));

// One block processes 8192 elements = 2048 float4 chunks (256 thr x 8 chunks).
// Plain (cached) loads: inputs were just restored by the harness -> L3-resident.
// Nontemporal stores: single-pass streaming writes, don't pollute L3.
#define CPT 8          // chunks per thread
#define NB_S   128     // blocks per S-region: 128*8192/8192
#define NB_CNT 2000    // blocks for count region: 128*128000/8192
#define NB_TOTAL (3 * NB_S + NB_CNT + 1)   // 2385

__global__ void __launch_bounds__(256)
k_fused(const int* __restrict__ tokens,
        const int* __restrict__ lti_in,
        const float* __restrict__ mask_in,
        const int* __restrict__ gen_in,
        const int* __restrict__ str_in,
        const int* __restrict__ gi_in,
        const int* __restrict__ cnt_in,
        float* __restrict__ out)
{
    const int bid = blockIdx.x;
    const int tid = threadIdx.x;

    if (bid < 3 * NB_S) {
        // ---- attention_mask / generated_tokens / generated_tokens_streaming ----
        const int region = bid >> 7;       // 0=mask, 1=gen, 2=str (block-uniform)
        const int rbid   = bid & 127;

        if (region == 0) {
            f32x4 v[CPT];
            #pragma unroll
            for (int j = 0; j < CPT; ++j) {
                const size_t e = ((size_t)(rbid * (256 * CPT) + j * 256 + tid)) << 2;
                v[j] = *(const f32x4*)(mask_in + e);        // cached load (L3 hit)
            }
            #pragma unroll
            for (int j = 0; j < CPT; ++j) {
                const int    c  = rbid * (256 * CPT) + j * 256 + tid;
                const int    b  = c >> 11;                  // 2048 chunks per S-row
                const int    s0 = (c & 2047) << 2;
                const int    lti_new = min(lti_in[b] + 1, SS - 1);
                if ((unsigned)(lti_new - s0) < 4u)
                    v[j][lti_new - s0] = 1.0f;
                __builtin_nontemporal_store(v[j], (f32x4*)(out + OFF_MASK + ((size_t)c << 2)));
            }
        } else {
            const int* src = (region == 1) ? gen_in : str_in;
            const int  dst = (region == 1) ? OFF_GEN : OFF_STR;
            i32x4 v[CPT];
            #pragma unroll
            for (int j = 0; j < CPT; ++j) {
                const size_t e = ((size_t)(rbid * (256 * CPT) + j * 256 + tid)) << 2;
                v[j] = *(const i32x4*)(src + e);            // cached load (L3 hit)
            }
            #pragma unroll
            for (int j = 0; j < CPT; ++j) {
                const int    c  = rbid * (256 * CPT) + j * 256 + tid;
                const int    b  = c >> 11;
                const int    s0 = (c & 2047) << 2;
                f32x4 go;
                go[0] = (float)v[j][0]; go[1] = (float)v[j][1];
                go[2] = (float)v[j][2]; go[3] = (float)v[j][3];
                const int gi_old = gi_in[b];                // scatter at PRE-increment idx
                if ((unsigned)(gi_old - s0) < 4u)
                    go[gi_old - s0] = (float)tokens[b];
                __builtin_nontemporal_store(go, (f32x4*)(out + dst + ((size_t)c << 2)));
            }
        }
    } else if (bid < 3 * NB_S + NB_CNT) {
        // ---- token_count: copy int->float, +1 at tokens[b] per row (no atomics) ----
        const int rbid = bid - 3 * NB_S;
        i32x4 v[CPT];
        #pragma unroll
        for (int j = 0; j < CPT; ++j) {
            const size_t e = ((size_t)(rbid * (256 * CPT) + j * 256 + tid)) << 2;
            v[j] = *(const i32x4*)(cnt_in + e);             // cached load (L3 hit)
        }
        #pragma unroll
        for (int j = 0; j < CPT; ++j) {
            const int    c  = rbid * (256 * CPT) + j * 256 + tid;
            const int    b  = c / 32000;                    // 32000 chunks per V-row
            const int    v0 = (c - b * 32000) << 2;
            f32x4 co;
            co[0] = (float)v[j][0]; co[1] = (float)v[j][1];
            co[2] = (float)v[j][2]; co[3] = (float)v[j][3];
            const int tok = tokens[b];
            if ((unsigned)(tok - v0) < 4u)
                co[tok - v0] += 1.0f;
            __builtin_nontemporal_store(co, (f32x4*)(out + OFF_CNT + ((size_t)c << 2)));
        }
    } else {
        // ---- tiny (B,) outputs: tokens, lti+1 clamped, gi+1 clamped ----
        if (tid < BB) {
            out[OFF_TOK + tid] = (float)tokens[tid];
            out[OFF_LTI + tid] = (float)min(lti_in[tid] + 1, SS - 1);
            out[OFF_GI  + tid] = (float)min(gi_in[tid] + 1, SS - 1);
        }
    }
}

extern "C" void kernel_launch(void* const* d_in, const int* in_sizes, int n_in,
                              void* d_out, int out_size, void* d_ws, size_t ws_size,
                              hipStream_t stream) {
    const int*   tokens = (const int*)  d_in[0];
    const int*   lti    = (const int*)  d_in[1];
    const float* mask   = (const float*)d_in[2];
    const int*   gen    = (const int*)  d_in[3];
    const int*   strm   = (const int*)  d_in[4];
    const int*   gi     = (const int*)  d_in[5];
    const int*   cnt    = (const int*)  d_in[6];
    float* out = (float*)d_out;

    k_fused<<<dim3(NB_TOTAL), dim3(256), 0, stream>>>(
        tokens, lti, mask, gen, strm, gi, cnt, out);
}

// Round 5
// 145.393 us; speedup vs baseline: 1.0141x; 1.0141x over previous
//
#include <hip/hip_runtime.h>

// Problem constants (match reference)
#define BB 128
#define SS 8192
#define VV 128000

// Output element offsets (flat float32 view of d_out, tuple return order)
#define OFF_TOK 0
#define OFF_LTI (OFF_TOK + BB)
#define OFF_MASK (OFF_LTI + BB)            // 256
#define OFF_GEN (OFF_MASK + BB * SS)       // 1048832
#define OFF_STR (OFF_GEN + BB * SS)        // 2097408
#define OFF_GI  (OFF_STR + BB * SS)        // 3145984
#define OFF_CNT (OFF_GI + BB)              // 3146112

// Native clang vectors — required by __builtin_nontemporal_{load,store}
typedef float f32x4 __attribute__((ext_vector_type(4)));
typedef int   i32x4 __attribute__((ext_vector_type(4)));

// Best-measured config (R3, 144.46 us): nontemporal loads AND stores,
// 4 chunks/thread, 4769 blocks. R4's cached-load + CPT=8 variant was
// neutral-to-worse (147.4) — single-pass streaming traffic; keep nt both ways.
#define NB_S   256     // blocks per S-region: 128*8192/4096
#define NB_CNT 4000    // blocks for count region: 128*128000/4096
#define NB_TOTAL (3 * NB_S + NB_CNT + 1)   // 4769

__global__ void __launch_bounds__(256)
k_fused(const int* __restrict__ tokens,
        const int* __restrict__ lti_in,
        const float* __restrict__ mask_in,
        const int* __restrict__ gen_in,
        const int* __restrict__ str_in,
        const int* __restrict__ gi_in,
        const int* __restrict__ cnt_in,
        float* __restrict__ out)
{
    const int bid = blockIdx.x;
    const int tid = threadIdx.x;

    if (bid < 3 * NB_S) {
        // ---- attention_mask / generated_tokens / generated_tokens_streaming ----
        const int region = bid >> 8;       // 0=mask, 1=gen, 2=str (block-uniform)
        const int rbid   = bid & 255;
        #pragma unroll
        for (int j = 0; j < 4; ++j) {
            const int    c  = rbid * 1024 + j * 256 + tid;  // float4 chunk in region
            const int    b  = c >> 11;                      // 2048 chunks per S-row
            const int    s0 = (c & 2047) << 2;              // first s covered by chunk
            const size_t e  = (size_t)c << 2;               // flat element offset

            if (region == 0) {
                f32x4 m = __builtin_nontemporal_load((const f32x4*)(mask_in + e));
                const int lti_new = min(lti_in[b] + 1, SS - 1);
                if ((unsigned)(lti_new - s0) < 4u)
                    m[lti_new - s0] = 1.0f;
                __builtin_nontemporal_store(m, (f32x4*)(out + OFF_MASK + e));
            } else {
                const int* src = (region == 1) ? gen_in : str_in;
                const int  dst = (region == 1) ? OFF_GEN : OFF_STR;
                i32x4 g = __builtin_nontemporal_load((const i32x4*)(src + e));
                f32x4 go;
                go[0] = (float)g[0]; go[1] = (float)g[1];
                go[2] = (float)g[2]; go[3] = (float)g[3];
                const int gi_old = gi_in[b];                // scatter at PRE-increment idx
                if ((unsigned)(gi_old - s0) < 4u)
                    go[gi_old - s0] = (float)tokens[b];
                __builtin_nontemporal_store(go, (f32x4*)(out + dst + e));
            }
        }
    } else if (bid < 3 * NB_S + NB_CNT) {
        // ---- token_count: copy int->float, +1 at tokens[b] per row (no atomics) ----
        const int rbid = bid - 3 * NB_S;
        #pragma unroll
        for (int j = 0; j < 4; ++j) {
            const int    c  = rbid * 1024 + j * 256 + tid;
            const int    b  = c / 32000;                    // 32000 chunks per V-row
            const int    v0 = (c - b * 32000) << 2;
            const size_t e  = (size_t)c << 2;

            i32x4 cc = __builtin_nontemporal_load((const i32x4*)(cnt_in + e));
            f32x4 co;
            co[0] = (float)cc[0]; co[1] = (float)cc[1];
            co[2] = (float)cc[2]; co[3] = (float)cc[3];
            const int tok = tokens[b];
            if ((unsigned)(tok - v0) < 4u)
                co[tok - v0] += 1.0f;
            __builtin_nontemporal_store(co, (f32x4*)(out + OFF_CNT + e));
        }
    } else {
        // ---- tiny (B,) outputs: tokens, lti+1 clamped, gi+1 clamped ----
        if (tid < BB) {
            out[OFF_TOK + tid] = (float)tokens[tid];
            out[OFF_LTI + tid] = (float)min(lti_in[tid] + 1, SS - 1);
            out[OFF_GI  + tid] = (float)min(gi_in[tid] + 1, SS - 1);
        }
    }
}

extern "C" void kernel_launch(void* const* d_in, const int* in_sizes, int n_in,
                              void* d_out, int out_size, void* d_ws, size_t ws_size,
                              hipStream_t stream) {
    const int*   tokens = (const int*)  d_in[0];
    const int*   lti    = (const int*)  d_in[1];
    const float* mask   = (const float*)d_in[2];
    const int*   gen    = (const int*)  d_in[3];
    const int*   strm   = (const int*)  d_in[4];
    const int*   gi     = (const int*)  d_in[5];
    const int*   cnt    = (const int*)  d_in[6];
    float* out = (float*)d_out;

    k_fused<<<dim3(NB_TOTAL), dim3(256), 0, stream>>>(
        tokens, lti, mask, gen, strm, gi, cnt, out);
}